// Round 14
// baseline (27.533 us; speedup 1.0000x reference)
//
#include <hip/hip_runtime.h>
#include <math.h>

#pragma clang fp contract(off)

#define NA      896
#define MAXDET  256
#define NBATCH  512
#define CAP     192
#define NCHUNK  14

typedef unsigned long long u64;
typedef unsigned int u32;

__device__ __forceinline__ u64 rl64(u64 v, int l) {
    u32 lo = __builtin_amdgcn_readlane((u32)v, l);
    u32 hi = __builtin_amdgcn_readlane((u32)(v >> 32), l);
    return ((u64)hi << 32) | (u64)lo;
}

struct FastSh {                 // ~33 KB
    float  det[CAP][17];
    float4 sbox[CAP];           // sorted boxes (matrix input)
    float4 sbox_u[CAP];         // unsorted boxes (written in Phase 1)
    u64    keys[CAP];
    int    slot_a[CAP];
    float  slot_s[CAP];
    int    rankv[CAP];
    u32    mat32[CAP][6];
    u32    cl[CAP][6];
};
struct SlowSh {                 // ~18 KB (correctness-only path, C > CAP)
    float  score[NA];
    float4 box[NA];
    u64    remw[NCHUNK];
};
union ShU { FastSh f; SlowSh s; };

// One batch per 8-wave block. Boxes decoded UNCONDITIONALLY in Phase 1
// (streaming load of each anchor's first 16B) so the matrix phase never
// waits on a dependent HBM gather; keypoint gather issued early in Phase 2,
// consumed only after the matrix phase. Pick set = fixpoint MIS (== greedy,
// unique-fixpoint induction); clusters via batched fc + LDS atomicOr.
__global__ __launch_bounds__(512, 4) void nms_kernel(
    const float* __restrict__ raw_box,
    const float* __restrict__ raw_score,
    const float* __restrict__ anchors,
    float* __restrict__ out,
    float* __restrict__ flags,
    float* __restrict__ gws, int has_ws)
{
    __shared__ ShU sh;
    __shared__ u64 Psh[3];
    __shared__ int stuck_sh;
    __shared__ int cnt[NCHUNK];

    const int b    = blockIdx.x;
    const int tid  = threadIdx.x;
    const int lane = tid & 63;
    const int wv   = tid >> 6;

    const float* sc_base = raw_score + (size_t)b * NA;
    float* out_b = out   + (size_t)b * MAXDET * 17;
    float* flg_b = flags + (size_t)b * MAXDET;

    // ---- Phase 1a: scores + unconditional box decode + per-chunk ballots ----
    float s_r[2]; u64 bal_r[2]; bool v_r[2]; float4 bx_r[2];
    #pragma unroll
    for (int r = 0; r < 2; ++r) {
        int c = wv + r * 8;
        s_r[r] = 0.0f; bal_r[r] = 0ull; v_r[r] = false;
        bx_r[r] = make_float4(0.f, 0.f, 0.f, 0.f);
        if (c < NCHUNK) {
            int a = c * 64 + lane;
            float x = sc_base[a];
            const float4 an = ((const float4*)anchors)[a];
            float4 r0 = *(const float4*)(raw_box + ((size_t)b * NA + a) * 16);
            x = fminf(fmaxf(x, -100.0f), 100.0f);
            float s = 1.0f / (1.0f + expf(-x));
            bool v = (s >= 0.75f);
            u64 bal = __ballot(v);
            // decode box corners (identical arithmetic to reference)
            float ax = an.x, ay = an.y, aw = an.z, ah = an.w;
            float xc = r0.x / 128.0f * aw + ax;
            float yc = r0.y / 128.0f * ah + ay;
            float w  = r0.z / 128.0f * aw;
            float h  = r0.w / 128.0f * ah;
            bx_r[r] = make_float4(yc - h * 0.5f, xc - w * 0.5f,
                                  yc + h * 0.5f, xc + w * 0.5f);
            s_r[r] = s; bal_r[r] = bal; v_r[r] = v;
            if (lane == 0) cnt[c] = (int)__popcll(bal);
        }
    }
    __syncthreads();

    // ---- Phase 1b: prefix + scatter (box corners go straight to LDS) ----
    int cn[NCHUNK];
    #pragma unroll
    for (int j = 0; j < NCHUNK; ++j) cn[j] = cnt[j];
    int C = 0;
    #pragma unroll
    for (int j = 0; j < NCHUNK; ++j) C += cn[j];

    if (C > CAP) {
        // ================= slow path: correctness-only =================
        if (!has_ws) {
            for (int t = tid; t < MAXDET * 17; t += 512) out_b[t] = 0.0f;
            for (int t = tid; t < MAXDET;      t += 512) flg_b[t] = 0.0f;
            return;
        }
        float* gdet = gws + (size_t)b * NA * 17;
        for (int a0 = tid; a0 < NA; a0 += 512) {
            float x = sc_base[a0];
            x = fminf(fmaxf(x, -100.0f), 100.0f);
            float s = 1.0f / (1.0f + expf(-x));
            const float4 an = ((const float4*)anchors)[a0];
            const float4* rb = (const float4*)(raw_box + ((size_t)b * NA + a0) * 16);
            float4 r0 = rb[0], r1 = rb[1], r2 = rb[2], r3 = rb[3];
            float ax = an.x, ay = an.y, aw = an.z, ah = an.w;
            float xc = r0.x / 128.0f * aw + ax;
            float yc = r0.y / 128.0f * ah + ay;
            float w  = r0.z / 128.0f * aw;
            float h  = r0.w / 128.0f * ah;
            float d0 = yc - h * 0.5f, d1 = xc - w * 0.5f;
            float d2 = yc + h * 0.5f, d3 = xc + w * 0.5f;
            sh.s.score[a0] = s;
            sh.s.box[a0]   = make_float4(d0, d1, d2, d3);
            float* gr = gdet + (size_t)a0 * 17;
            gr[0] = d0; gr[1] = d1; gr[2] = d2; gr[3] = d3;
            float kp[12] = {r1.x, r1.y, r1.z, r1.w,
                            r2.x, r2.y, r2.z, r2.w,
                            r3.x, r3.y, r3.z, r3.w};
            #pragma unroll
            for (int t = 0; t < 6; ++t) {
                gr[4 + 2 * t] = kp[2 * t]     / 128.0f * aw + ax;
                gr[5 + 2 * t] = kp[2 * t + 1] / 128.0f * ah + ay;
            }
            gr[16] = s;
            u64 bal = __ballot(s >= 0.75f);
            if (lane == 0) sh.s.remw[a0 >> 6] = bal;
        }
        __syncthreads();
        if (wv == 0) {
            int step = 0;
            for (; step < MAXDET; ++step) {
                u64 best = 0;
                for (int c = 0; c < NCHUNK; ++c) {
                    if ((sh.s.remw[c] >> lane) & 1ull) {
                        int a = c * 64 + lane;
                        u64 key = ((u64)__float_as_uint(sh.s.score[a]) << 10)
                                | (u64)(1023 - a);
                        if (key > best) best = key;
                    }
                }
                #pragma unroll
                for (int off = 32; off; off >>= 1) {
                    u64 o = __shfl_xor(best, off);
                    if (o > best) best = o;
                }
                if (best == 0) break;
                int idx = 1023 - (int)(best & 1023ull);
                float4 bb = sh.s.box[idx];
                float areaA = (bb.z - bb.x) * (bb.w - bb.y);
                u32 ov = 0; int n = 0;
                for (int c = 0; c < NCHUNK; ++c) {
                    bool o = false;
                    if ((sh.s.remw[c] >> lane) & 1ull) {
                        int a = c * 64 + lane;
                        float4 cb = sh.s.box[a];
                        float i0 = fmaxf(bb.x, cb.x), i1 = fmaxf(bb.y, cb.y);
                        float i2 = fminf(bb.z, cb.z), i3 = fminf(bb.w, cb.w);
                        float inter = (i2 - i0) * (i3 - i1);
                        float areaB = (cb.z - cb.x) * (cb.w - cb.y);
                        float q = inter / (areaA + areaB - inter);
                        o = (q > 0.3f);
                    }
                    u64 balc = __ballot(o);
                    if (o) ov |= 1u << c;
                    n += (int)__popcll(balc);
                    if (lane == 0) sh.s.remw[c] &= ~balc;
                }
                if (n <= 1) {
                    if (lane < 17) out_b[step * 17 + lane] = gdet[(size_t)idx * 17 + lane];
                    if (lane == 17) flg_b[step] = 1.0f;
                } else {
                    float tot = 0.0f, wcv[16];
                    #pragma unroll
                    for (int j = 0; j < 16; ++j) wcv[j] = 0.0f;
                    for (int c = 0; c < NCHUNK; ++c) {
                        if ((ov >> c) & 1u) {
                            int a = c * 64 + lane;
                            float s2 = sh.s.score[a]; tot += s2;
                            #pragma unroll
                            for (int j = 0; j < 16; ++j)
                                wcv[j] += gdet[(size_t)a * 17 + j] * s2;
                        }
                    }
                    #pragma unroll
                    for (int off = 32; off; off >>= 1) {
                        tot += __shfl_xor(tot, off);
                        #pragma unroll
                        for (int j = 0; j < 16; ++j) wcv[j] += __shfl_xor(wcv[j], off);
                    }
                    if (lane == 0) {
                        float safe = (tot > 0.0f) ? tot : 1.0f;
                        #pragma unroll
                        for (int j = 0; j < 16; ++j) out_b[step * 17 + j] = wcv[j] / safe;
                        out_b[step * 17 + 16] = tot / (float)n;
                        flg_b[step] = 1.0f;
                    }
                }
            }
            for (int t = step * 17 + lane; t < MAXDET * 17; t += 64) out_b[t] = 0.0f;
            for (int t = step + lane;      t < MAXDET;      t += 64) flg_b[t] = 0.0f;
        }
        return;
        // ===============================================================
    }

    #pragma unroll
    for (int r = 0; r < 2; ++r) {
        int c = wv + r * 8;
        if (c < NCHUNK && v_r[r]) {
            int base = 0;
            #pragma unroll
            for (int j = 0; j < NCHUNK; ++j) base += (j < c) ? cn[j] : 0;
            int slot = base + (int)__popcll(bal_r[r] & ((1ull << lane) - 1ull));
            int a = c * 64 + lane;
            sh.f.keys[slot]   = ((u64)__float_as_uint(s_r[r]) << 10) | (u64)(1023 - a);
            sh.f.slot_a[slot] = a;
            sh.f.slot_s[slot] = s_r[r];
            sh.f.sbox_u[slot] = bx_r[r];
        }
    }
    __syncthreads();

    // ---- Phase 2a: issue KP gather (consumed after matrix) + ballot-rank ----
    float4 an2, g1, g2, g3;
    if (tid < C) {
        int a_my = sh.f.slot_a[tid];
        an2 = ((const float4*)anchors)[a_my];
        const float4* rb = (const float4*)(raw_box + ((size_t)b * NA + a_my) * 16);
        g1 = rb[1]; g2 = rb[2]; g3 = rb[3];
    }
    {
        u64 k0 = (lane < C)       ? sh.f.keys[lane]       : 0ull;
        u64 k1 = (lane + 64 < C)  ? sh.f.keys[lane + 64]  : 0ull;
        u64 k2 = (lane + 128 < C) ? sh.f.keys[lane + 128] : 0ull;
        int i = wv;
        if (i < C) {
            u64 ki = sh.f.keys[i];
            for (;;) {
                int inext = i + 8;
                u64 knext = (inext < C) ? sh.f.keys[inext] : 0ull;  // prefetch
                int q = (int)__popcll(__ballot(k0 > ki))
                      + (int)__popcll(__ballot(k1 > ki))
                      + (int)__popcll(__ballot(k2 > ki));
                if (lane == 0) sh.f.rankv[i] = q;
                if (inext >= C) break;
                i = inext; ki = knext;
            }
        }
    }
    __syncthreads();

    // ---- Phase 2b: sorted scatter (boxes + score; kp deferred) ----
    int q_my = 0;
    if (tid < C) {
        q_my = sh.f.rankv[tid];
        float4 bx = sh.f.sbox_u[tid];
        sh.f.det[q_my][0] = bx.x; sh.f.det[q_my][1] = bx.y;
        sh.f.det[q_my][2] = bx.z; sh.f.det[q_my][3] = bx.w;
        sh.f.det[q_my][16] = sh.f.slot_s[tid];
        sh.f.sbox[q_my] = bx;
    }
    __syncthreads();

    // ---- Phase 3: overlap bitmatrix, one u32 word (32 cols) per thread ----
    const int words = (C + 31) >> 5;
    for (int u = tid; u < C * words; u += 512) {
        int w = u / C;
        int row = u - w * C;
        int kbase = w << 5;
        int ke = C - kbase; if (ke > 32) ke = 32;
        float4 sb = sh.f.sbox[row];
        float ar = (sb.z - sb.x) * (sb.w - sb.y);
        u32 mm = 0, bit = 1u;
        #pragma unroll 4
        for (int k = 0; k < ke; ++k, bit <<= 1) {
            float4 bk = sh.f.sbox[kbase + k];
            float ak = (bk.z - bk.x) * (bk.w - bk.y);
            float i0 = fmaxf(sb.x, bk.x), i1 = fmaxf(sb.y, bk.y);
            float i2 = fminf(sb.z, bk.z), i3 = fminf(sb.w, bk.w);
            float inter = (i2 - i0) * (i3 - i1);
            float qq = inter / (ar + ak - inter);   // NaN -> no bit
            if (qq > 0.3f) mm |= bit;
        }
        sh.f.mat32[row][w] = mm;
    }
    // KP gather has landed by now (hidden under rank + matrix): decode kps
    if (tid < C) {
        float ax = an2.x, ay = an2.y, aw = an2.z, ah = an2.w;
        float kp[12] = {g1.x, g1.y, g1.z, g1.w,
                        g2.x, g2.y, g2.z, g2.w,
                        g3.x, g3.y, g3.z, g3.w};
        #pragma unroll
        for (int t = 0; t < 6; ++t) {
            sh.f.det[q_my][4 + 2 * t] = kp[2 * t]     / 128.0f * aw + ax;
            sh.f.det[q_my][5 + 2 * t] = kp[2 * t + 1] / 128.0f * ah + ay;
        }
    }
    __syncthreads();

    // valid-candidate masks (scrub unwritten matrix words)
    const u64 V0 = (C >= 64)  ? ~0ull : ((C > 0)   ? ((1ull << C) - 1)         : 0ull);
    const u64 V1 = (C >= 128) ? ~0ull : ((C > 64)  ? ((1ull << (C - 64)) - 1)  : 0ull);
    const u64 V2 = (C >= 192) ? ~0ull : ((C > 128) ? ((1ull << (C - 128)) - 1) : 0ull);

    // ---- Phase 4: wave 0 pick set (fixpoint MIS); waves 1-7 zero cl+out ----
    if (wv == 0) {
        const u32 (*M)[6] = sh.f.mat32;
        const bool vA = (lane < C), vB = (lane + 64 < C), vC = (lane + 128 < C);
        u64 A0 = vA ? ((u64)M[lane][0]       | ((u64)M[lane][1] << 32))       : 0ull;
        u64 B0 = vB ? ((u64)M[lane + 64][0]  | ((u64)M[lane + 64][1] << 32))  : 0ull;
        u64 B1 = vB ? ((u64)M[lane + 64][2]  | ((u64)M[lane + 64][3] << 32))  : 0ull;
        u64 C0 = vC ? ((u64)M[lane + 128][0] | ((u64)M[lane + 128][1] << 32)) : 0ull;
        u64 C1 = vC ? ((u64)M[lane + 128][2] | ((u64)M[lane + 128][3] << 32)) : 0ull;
        u64 C2 = vC ? ((u64)M[lane + 128][4] | ((u64)M[lane + 128][5] << 32)) : 0ull;
        A0 &= V0; B0 &= V0; B1 &= V1; C0 &= V0; C1 &= V1; C2 &= V2;

        const u64 bel = lane ? ((1ull << lane) - 1ull) : 0ull;

        bool degen = (__ballot((vA && !((A0 >> lane) & 1ull)) ||
                               (vB && !((B1 >> lane) & 1ull)) ||
                               (vC && !((C2 >> lane) & 1ull))) != 0ull);
        u64 P0 = V0, P1 = V1, P2 = V2;
        bool ok = false;
        if (!degen) {
            for (int round = 0; round < 32; ++round) {
                bool a0 = vA && !(A0 & P0 & bel);
                bool a1 = vB && !((B0 & P0) | (B1 & P1 & bel));
                bool a2 = vC && !((C0 & P0) | (C1 & P1) | (C2 & P2 & bel));
                u64 n0 = __ballot(a0), n1 = __ballot(a1), n2 = __ballot(a2);
                if (n0 == P0 && n1 == P1 && n2 == P2) { ok = true; break; }
                P0 = n0; P1 = n1; P2 = n2;
            }
        }
        int stk = CAP;
        if (!ok) {
            // serial fallback (bit-exact incl. degenerate freeze semantics)
            u64 r00 = vA ? (((u64)M[lane][0] | ((u64)M[lane][1] << 32)) & V0) : 0ull;
            u64 r01 = vA ? (((u64)M[lane][2] | ((u64)M[lane][3] << 32)) & V1) : 0ull;
            u64 r02 = vA ? (((u64)M[lane][4] | ((u64)M[lane][5] << 32)) & V2) : 0ull;
            u64 r11 = B1;
            u64 r12 = vB ? (((u64)M[lane + 64][4] | ((u64)M[lane + 64][5] << 32)) & V2) : 0ull;
            u64 r22 = C2;
            u64 rem0 = V0, rem1 = V1, rem2 = V2;
            P0 = 0; P1 = 0; P2 = 0;
            while (rem0) {
                int i = (int)__builtin_ctzll(rem0);
                u64 w0 = rl64(r00, i), w1 = rl64(r01, i), w2 = rl64(r02, i);
                if (!((w0 >> i) & 1ull)) { stk = i; break; }
                P0 |= 1ull << i;
                rem0 &= ~w0; rem1 &= ~w1; rem2 &= ~w2;
            }
            if (stk == CAP) while (rem1) {
                int i = (int)__builtin_ctzll(rem1);
                u64 w1 = rl64(r11, i), w2 = rl64(r12, i);
                if (!((w1 >> i) & 1ull)) { stk = 64 + i; break; }
                P1 |= 1ull << i;
                rem1 &= ~w1; rem2 &= ~w2;
            }
            if (stk == CAP) while (rem2) {
                int i = (int)__builtin_ctzll(rem2);
                u64 w2 = rl64(r22, i);
                if (!((w2 >> i) & 1ull)) { stk = 128 + i; break; }
                P2 |= 1ull << i;
                rem2 &= ~w2;
            }
        }
        if (lane == 0) { Psh[0] = P0; Psh[1] = P1; Psh[2] = P2; stuck_sh = stk; }
    } else {
        for (int t = tid - 64; t < CAP * 6;     t += 448) ((u32*)sh.f.cl)[t] = 0u;
        for (int t = tid - 64; t < MAXDET * 17; t += 448) out_b[t] = 0.0f;
        for (int t = tid - 64; t < MAXDET;      t += 448) flg_b[t] = 0.0f;
    }
    __syncthreads();

    const u64 P0 = Psh[0], P1 = Psh[1], P2 = Psh[2];
    const int stuck_v = stuck_sh;

    // ---- Phase 5: batched remover-scatter: cl[fc(k)] |= bit(k) ----
    if (tid < C) {
        u64 q0 = ((u64)sh.f.mat32[tid][0] | ((u64)sh.f.mat32[tid][1] << 32)) & P0;
        u64 q1 = ((u64)sh.f.mat32[tid][2] | ((u64)sh.f.mat32[tid][3] << 32)) & P1;
        u64 q2 = ((u64)sh.f.mat32[tid][4] | ((u64)sh.f.mat32[tid][5] << 32)) & P2;
        int fc = -1;
        if      (q0) fc = (int)__builtin_ctzll(q0);
        else if (q1) fc = 64  + (int)__builtin_ctzll(q1);
        else if (q2) fc = 128 + (int)__builtin_ctzll(q2);
        if (fc >= 0) atomicOr(&sh.f.cl[fc][tid >> 5], 1u << (tid & 31));
    }
    __syncthreads();

    // ---- Phase 6: parallel emission by pick rank ----
    bool is_pick = false;
    if (tid < C) {
        is_pick = (tid < 64)  ? ((P0 >> tid) & 1ull)
                : (tid < 128) ? ((P1 >> (tid - 64)) & 1ull)
                              : ((P2 >> (tid - 128)) & 1ull);
    }
    if (is_pick && tid < ((stuck_v < CAP) ? stuck_v : CAP)) {
        int s;
        if (tid < 64)
            s = (int)__popcll(P0 & ((tid ? ((1ull << tid) - 1) : 0ull)));
        else if (tid < 128)
            s = (int)__popcll(P0)
              + (int)__popcll(P1 & (((tid - 64) ? ((1ull << (tid - 64)) - 1) : 0ull)));
        else
            s = (int)__popcll(P0) + (int)__popcll(P1)
              + (int)__popcll(P2 & (((tid - 128) ? ((1ull << (tid - 128)) - 1) : 0ull)));

        u64 c0 = (u64)sh.f.cl[tid][0] | ((u64)sh.f.cl[tid][1] << 32);
        u64 c1 = (u64)sh.f.cl[tid][2] | ((u64)sh.f.cl[tid][3] << 32);
        u64 c2 = (u64)sh.f.cl[tid][4] | ((u64)sh.f.cl[tid][5] << 32);
        int n = (int)__popcll(c0) + (int)__popcll(c1) + (int)__popcll(c2);
        float* orow = out_b + s * 17;
        if (n <= 1) {
            #pragma unroll
            for (int c = 0; c < 17; ++c) orow[c] = sh.f.det[tid][c];
        } else {
            float tot = 0.0f, wc[16];
            #pragma unroll
            for (int c = 0; c < 16; ++c) wc[c] = 0.0f;
            u64 m = c0;
            while (m) { int k = (int)__builtin_ctzll(m); m &= m - 1;
                float sc = sh.f.det[k][16]; tot += sc;
                #pragma unroll
                for (int c = 0; c < 16; ++c) wc[c] += sh.f.det[k][c] * sc; }
            m = c1;
            while (m) { int k = 64 + (int)__builtin_ctzll(m); m &= m - 1;
                float sc = sh.f.det[k][16]; tot += sc;
                #pragma unroll
                for (int c = 0; c < 16; ++c) wc[c] += sh.f.det[k][c] * sc; }
            m = c2;
            while (m) { int k = 128 + (int)__builtin_ctzll(m); m &= m - 1;
                float sc = sh.f.det[k][16]; tot += sc;
                #pragma unroll
                for (int c = 0; c < 16; ++c) wc[c] += sh.f.det[k][c] * sc; }
            float safe = (tot > 0.0f) ? tot : 1.0f;
            #pragma unroll
            for (int c = 0; c < 16; ++c) orow[c] = wc[c] / safe;
            orow[16] = tot / (float)n;
        }
        flg_b[s] = 1.0f;
    }
    // frozen-tail replication for the (unreachable) degenerate case
    if (stuck_v < CAP) {
        int Pb = 0;   // picks before the stuck index
        {
            u64 t0 = P0, t1 = P1, t2 = P2;
            if (stuck_v < 64)       { t0 &= (stuck_v ? ((1ull << stuck_v) - 1) : 0ull); t1 = 0; t2 = 0; }
            else if (stuck_v < 128) { t1 &= (((stuck_v - 64) ? ((1ull << (stuck_v - 64)) - 1) : 0ull)); t2 = 0; }
            else                    { t2 &= (((stuck_v - 128) ? ((1ull << (stuck_v - 128)) - 1) : 0ull)); }
            Pb = (int)__popcll(t0) + (int)__popcll(t1) + (int)__popcll(t2);
        }
        for (int s2 = Pb + tid; s2 < MAXDET; s2 += 512) {
            float* orow = out_b + s2 * 17;
            #pragma unroll
            for (int c = 0; c < 17; ++c) orow[c] = sh.f.det[stuck_v][c];
            flg_b[s2] = 1.0f;
        }
    }
}

extern "C" void kernel_launch(void* const* d_in, const int* in_sizes, int n_in,
                              void* d_out, int out_size, void* d_ws, size_t ws_size,
                              hipStream_t stream) {
    const float* raw_box   = (const float*)d_in[0];
    const float* raw_score = (const float*)d_in[1];
    const float* anchors   = (const float*)d_in[2];
    float* out   = (float*)d_out;
    float* flags = out + (size_t)NBATCH * MAXDET * 17;
    int has_ws = (ws_size >= (size_t)NBATCH * NA * 17 * sizeof(float)) ? 1 : 0;
    nms_kernel<<<NBATCH, 512, 0, stream>>>(raw_box, raw_score, anchors, out, flags,
                                           (float*)d_ws, has_ws);
}

// Round 15
// 26.016 us; speedup vs baseline: 1.0583x; 1.0583x over previous
//
#include <hip/hip_runtime.h>
#include <math.h>

#pragma clang fp contract(off)

#define NA      896
#define MAXDET  256
#define NBATCH  512
#define CAP     192
#define NCHUNK  14

typedef unsigned long long u64;
typedef unsigned int u32;

__device__ __forceinline__ u64 rl64(u64 v, int l) {
    u32 lo = __builtin_amdgcn_readlane((u32)v, l);
    u32 hi = __builtin_amdgcn_readlane((u32)(v >> 32), l);
    return ((u64)hi << 32) | (u64)lo;
}

struct FastSh {                 // ~30 KB
    float  det[CAP][17];
    float4 sbox[CAP];
    u64    keys[CAP];
    int    slot_a[CAP];
    float  slot_s[CAP];
    int    rankv[CAP];
    u32    mat32[CAP][6];
    u32    cl[CAP][6];
};
struct SlowSh {                 // ~18 KB (correctness-only path, C > CAP)
    float  score[NA];
    float4 box[NA];
    u64    remw[NCHUNK];
};
union ShU { FastSh f; SlowSh s; };

// One batch per 8-wave block (empirical-best R10/R13 structure). Pick set =
// lexicographically-first MIS of the symmetric overlap graph via parallel
// fixpoint (== greedy NMS set, unique-fixpoint induction). Clusters via
// batched fc + LDS atomicOr scatter. Rank loop software-pipelined.
__global__ __launch_bounds__(512, 4) void nms_kernel(
    const float* __restrict__ raw_box,
    const float* __restrict__ raw_score,
    const float* __restrict__ anchors,
    float* __restrict__ out,
    float* __restrict__ flags,
    float* __restrict__ gws, int has_ws)
{
    __shared__ ShU sh;
    __shared__ u64 Psh[3];
    __shared__ int stuck_sh;
    __shared__ int cnt[NCHUNK];

    const int b    = blockIdx.x;
    const int tid  = threadIdx.x;
    const int lane = tid & 63;
    const int wv   = tid >> 6;

    const float* sc_base = raw_score + (size_t)b * NA;
    float* out_b = out   + (size_t)b * MAXDET * 17;
    float* flg_b = flags + (size_t)b * MAXDET;

    // ---- Phase 1a: scores + per-chunk ballots ----
    float s_r[2]; u64 bal_r[2]; bool v_r[2];
    #pragma unroll
    for (int r = 0; r < 2; ++r) {
        int c = wv + r * 8;
        s_r[r] = 0.0f; bal_r[r] = 0ull; v_r[r] = false;
        if (c < NCHUNK) {
            int a = c * 64 + lane;
            float x = sc_base[a];
            x = fminf(fmaxf(x, -100.0f), 100.0f);
            float s = 1.0f / (1.0f + expf(-x));
            bool v = (s >= 0.75f);
            u64 bal = __ballot(v);
            s_r[r] = s; bal_r[r] = bal; v_r[r] = v;
            if (lane == 0) cnt[c] = (int)__popcll(bal);
        }
    }
    __syncthreads();

    // ---- Phase 1b: prefix + scatter (keys carry anchor tiebreak) ----
    int cn[NCHUNK];
    #pragma unroll
    for (int j = 0; j < NCHUNK; ++j) cn[j] = cnt[j];
    int C = 0;
    #pragma unroll
    for (int j = 0; j < NCHUNK; ++j) C += cn[j];

    if (C > CAP) {
        // ================= slow path: correctness-only =================
        if (!has_ws) {
            for (int t = tid; t < MAXDET * 17; t += 512) out_b[t] = 0.0f;
            for (int t = tid; t < MAXDET;      t += 512) flg_b[t] = 0.0f;
            return;
        }
        float* gdet = gws + (size_t)b * NA * 17;
        for (int a0 = tid; a0 < NA; a0 += 512) {
            float x = sc_base[a0];
            x = fminf(fmaxf(x, -100.0f), 100.0f);
            float s = 1.0f / (1.0f + expf(-x));
            const float4 an = ((const float4*)anchors)[a0];
            const float4* rb = (const float4*)(raw_box + ((size_t)b * NA + a0) * 16);
            float4 r0 = rb[0], r1 = rb[1], r2 = rb[2], r3 = rb[3];
            float ax = an.x, ay = an.y, aw = an.z, ah = an.w;
            float xc = r0.x / 128.0f * aw + ax;
            float yc = r0.y / 128.0f * ah + ay;
            float w  = r0.z / 128.0f * aw;
            float h  = r0.w / 128.0f * ah;
            float d0 = yc - h * 0.5f, d1 = xc - w * 0.5f;
            float d2 = yc + h * 0.5f, d3 = xc + w * 0.5f;
            sh.s.score[a0] = s;
            sh.s.box[a0]   = make_float4(d0, d1, d2, d3);
            float* gr = gdet + (size_t)a0 * 17;
            gr[0] = d0; gr[1] = d1; gr[2] = d2; gr[3] = d3;
            float kp[12] = {r1.x, r1.y, r1.z, r1.w,
                            r2.x, r2.y, r2.z, r2.w,
                            r3.x, r3.y, r3.z, r3.w};
            #pragma unroll
            for (int t = 0; t < 6; ++t) {
                gr[4 + 2 * t] = kp[2 * t]     / 128.0f * aw + ax;
                gr[5 + 2 * t] = kp[2 * t + 1] / 128.0f * ah + ay;
            }
            gr[16] = s;
            u64 bal = __ballot(s >= 0.75f);
            if (lane == 0) sh.s.remw[a0 >> 6] = bal;
        }
        __syncthreads();
        if (wv == 0) {
            int step = 0;
            for (; step < MAXDET; ++step) {
                u64 best = 0;
                for (int c = 0; c < NCHUNK; ++c) {
                    if ((sh.s.remw[c] >> lane) & 1ull) {
                        int a = c * 64 + lane;
                        u64 key = ((u64)__float_as_uint(sh.s.score[a]) << 10)
                                | (u64)(1023 - a);
                        if (key > best) best = key;
                    }
                }
                #pragma unroll
                for (int off = 32; off; off >>= 1) {
                    u64 o = __shfl_xor(best, off);
                    if (o > best) best = o;
                }
                if (best == 0) break;
                int idx = 1023 - (int)(best & 1023ull);
                float4 bb = sh.s.box[idx];
                float areaA = (bb.z - bb.x) * (bb.w - bb.y);
                u32 ov = 0; int n = 0;
                for (int c = 0; c < NCHUNK; ++c) {
                    bool o = false;
                    if ((sh.s.remw[c] >> lane) & 1ull) {
                        int a = c * 64 + lane;
                        float4 cb = sh.s.box[a];
                        float i0 = fmaxf(bb.x, cb.x), i1 = fmaxf(bb.y, cb.y);
                        float i2 = fminf(bb.z, cb.z), i3 = fminf(bb.w, cb.w);
                        float inter = (i2 - i0) * (i3 - i1);
                        float areaB = (cb.z - cb.x) * (cb.w - cb.y);
                        float q = inter / (areaA + areaB - inter);
                        o = (q > 0.3f);
                    }
                    u64 balc = __ballot(o);
                    if (o) ov |= 1u << c;
                    n += (int)__popcll(balc);
                    if (lane == 0) sh.s.remw[c] &= ~balc;
                }
                if (n <= 1) {
                    if (lane < 17) out_b[step * 17 + lane] = gdet[(size_t)idx * 17 + lane];
                    if (lane == 17) flg_b[step] = 1.0f;
                } else {
                    float tot = 0.0f, wcv[16];
                    #pragma unroll
                    for (int j = 0; j < 16; ++j) wcv[j] = 0.0f;
                    for (int c = 0; c < NCHUNK; ++c) {
                        if ((ov >> c) & 1u) {
                            int a = c * 64 + lane;
                            float s2 = sh.s.score[a]; tot += s2;
                            #pragma unroll
                            for (int j = 0; j < 16; ++j)
                                wcv[j] += gdet[(size_t)a * 17 + j] * s2;
                        }
                    }
                    #pragma unroll
                    for (int off = 32; off; off >>= 1) {
                        tot += __shfl_xor(tot, off);
                        #pragma unroll
                        for (int j = 0; j < 16; ++j) wcv[j] += __shfl_xor(wcv[j], off);
                    }
                    if (lane == 0) {
                        float safe = (tot > 0.0f) ? tot : 1.0f;
                        #pragma unroll
                        for (int j = 0; j < 16; ++j) out_b[step * 17 + j] = wcv[j] / safe;
                        out_b[step * 17 + 16] = tot / (float)n;
                        flg_b[step] = 1.0f;
                    }
                }
            }
            for (int t = step * 17 + lane; t < MAXDET * 17; t += 64) out_b[t] = 0.0f;
            for (int t = step + lane;      t < MAXDET;      t += 64) flg_b[t] = 0.0f;
        }
        return;
        // ===============================================================
    }

    #pragma unroll
    for (int r = 0; r < 2; ++r) {
        int c = wv + r * 8;
        if (c < NCHUNK && v_r[r]) {
            int base = 0;
            #pragma unroll
            for (int j = 0; j < NCHUNK; ++j) base += (j < c) ? cn[j] : 0;
            int slot = base + (int)__popcll(bal_r[r] & ((1ull << lane) - 1ull));
            int a = c * 64 + lane;
            sh.f.keys[slot]   = ((u64)__float_as_uint(s_r[r]) << 10) | (u64)(1023 - a);
            sh.f.slot_a[slot] = a;
            sh.f.slot_s[slot] = s_r[r];
        }
    }
    __syncthreads();

    // ---- Phase 2a: issue gather loads + software-pipelined ballot-rank ----
    float4 an, g0, g1, g2, g3; float s_my = 0.0f;
    if (tid < C) {
        int a_my = sh.f.slot_a[tid];
        s_my = sh.f.slot_s[tid];
        an = ((const float4*)anchors)[a_my];
        const float4* rb = (const float4*)(raw_box + ((size_t)b * NA + a_my) * 16);
        g0 = rb[0]; g1 = rb[1]; g2 = rb[2]; g3 = rb[3];
    }
    {
        u64 k0 = (lane < C)       ? sh.f.keys[lane]       : 0ull;
        u64 k1 = (lane + 64 < C)  ? sh.f.keys[lane + 64]  : 0ull;
        u64 k2 = (lane + 128 < C) ? sh.f.keys[lane + 128] : 0ull;
        int i = wv;
        if (i < C) {
            u64 ki = sh.f.keys[i];
            for (;;) {
                int inext = i + 8;
                u64 knext = (inext < C) ? sh.f.keys[inext] : 0ull;  // prefetch
                int q = (int)__popcll(__ballot(k0 > ki))
                      + (int)__popcll(__ballot(k1 > ki))
                      + (int)__popcll(__ballot(k2 > ki));
                if (lane == 0) sh.f.rankv[i] = q;
                if (inext >= C) break;
                i = inext; ki = knext;
            }
        }
    }
    __syncthreads();

    // ---- Phase 2b: decode into sorted position det[q] ----
    if (tid < C) {
        int q = sh.f.rankv[tid];
        float ax = an.x, ay = an.y, aw = an.z, ah = an.w;
        float xc = g0.x / 128.0f * aw + ax;
        float yc = g0.y / 128.0f * ah + ay;
        float w  = g0.z / 128.0f * aw;
        float h  = g0.w / 128.0f * ah;
        float d0 = yc - h * 0.5f, d1 = xc - w * 0.5f;
        float d2 = yc + h * 0.5f, d3 = xc + w * 0.5f;
        sh.f.det[q][0] = d0; sh.f.det[q][1] = d1;
        sh.f.det[q][2] = d2; sh.f.det[q][3] = d3;
        sh.f.det[q][16] = s_my;
        sh.f.sbox[q] = make_float4(d0, d1, d2, d3);
        float kp[12] = {g1.x, g1.y, g1.z, g1.w,
                        g2.x, g2.y, g2.z, g2.w,
                        g3.x, g3.y, g3.z, g3.w};
        #pragma unroll
        for (int t = 0; t < 6; ++t) {
            sh.f.det[q][4 + 2 * t] = kp[2 * t]     / 128.0f * aw + ax;
            sh.f.det[q][5 + 2 * t] = kp[2 * t + 1] / 128.0f * ah + ay;
        }
    }
    __syncthreads();

    // ---- Phase 3: overlap bitmatrix, one u32 word (32 cols) per thread ----
    const int words = (C + 31) >> 5;
    for (int u = tid; u < C * words; u += 512) {
        int w = u / C;
        int row = u - w * C;
        int kbase = w << 5;
        int ke = C - kbase; if (ke > 32) ke = 32;
        float4 sb = sh.f.sbox[row];
        float ar = (sb.z - sb.x) * (sb.w - sb.y);
        u32 mm = 0, bit = 1u;
        #pragma unroll 4
        for (int k = 0; k < ke; ++k, bit <<= 1) {
            float4 bk = sh.f.sbox[kbase + k];
            float ak = (bk.z - bk.x) * (bk.w - bk.y);
            float i0 = fmaxf(sb.x, bk.x), i1 = fmaxf(sb.y, bk.y);
            float i2 = fminf(sb.z, bk.z), i3 = fminf(sb.w, bk.w);
            float inter = (i2 - i0) * (i3 - i1);
            float qq = inter / (ar + ak - inter);   // NaN -> no bit
            if (qq > 0.3f) mm |= bit;
        }
        sh.f.mat32[row][w] = mm;
    }
    __syncthreads();

    // valid-candidate masks (scrub unwritten matrix words)
    const u64 V0 = (C >= 64)  ? ~0ull : ((C > 0)   ? ((1ull << C) - 1)         : 0ull);
    const u64 V1 = (C >= 128) ? ~0ull : ((C > 64)  ? ((1ull << (C - 64)) - 1)  : 0ull);
    const u64 V2 = (C >= 192) ? ~0ull : ((C > 128) ? ((1ull << (C - 128)) - 1) : 0ull);

    // ---- Phase 4: wave 0 pick set (fixpoint MIS); waves 1-7 zero cl+out ----
    if (wv == 0) {
        const u32 (*M)[6] = sh.f.mat32;
        const bool vA = (lane < C), vB = (lane + 64 < C), vC = (lane + 128 < C);
        u64 A0 = vA ? ((u64)M[lane][0]       | ((u64)M[lane][1] << 32))       : 0ull;
        u64 B0 = vB ? ((u64)M[lane + 64][0]  | ((u64)M[lane + 64][1] << 32))  : 0ull;
        u64 B1 = vB ? ((u64)M[lane + 64][2]  | ((u64)M[lane + 64][3] << 32))  : 0ull;
        u64 C0 = vC ? ((u64)M[lane + 128][0] | ((u64)M[lane + 128][1] << 32)) : 0ull;
        u64 C1 = vC ? ((u64)M[lane + 128][2] | ((u64)M[lane + 128][3] << 32)) : 0ull;
        u64 C2 = vC ? ((u64)M[lane + 128][4] | ((u64)M[lane + 128][5] << 32)) : 0ull;
        A0 &= V0; B0 &= V0; B1 &= V1; C0 &= V0; C1 &= V1; C2 &= V2;

        const u64 bel = lane ? ((1ull << lane) - 1ull) : 0ull;

        bool degen = (__ballot((vA && !((A0 >> lane) & 1ull)) ||
                               (vB && !((B1 >> lane) & 1ull)) ||
                               (vC && !((C2 >> lane) & 1ull))) != 0ull);
        u64 P0 = V0, P1 = V1, P2 = V2;
        bool ok = false;
        if (!degen) {
            for (int round = 0; round < 32; ++round) {
                bool a0 = vA && !(A0 & P0 & bel);
                bool a1 = vB && !((B0 & P0) | (B1 & P1 & bel));
                bool a2 = vC && !((C0 & P0) | (C1 & P1) | (C2 & P2 & bel));
                u64 n0 = __ballot(a0), n1 = __ballot(a1), n2 = __ballot(a2);
                if (n0 == P0 && n1 == P1 && n2 == P2) { ok = true; break; }
                P0 = n0; P1 = n1; P2 = n2;
            }
        }
        int stk = CAP;
        if (!ok) {
            // serial fallback (bit-exact incl. degenerate freeze semantics)
            u64 r00 = vA ? (((u64)M[lane][0] | ((u64)M[lane][1] << 32)) & V0) : 0ull;
            u64 r01 = vA ? (((u64)M[lane][2] | ((u64)M[lane][3] << 32)) & V1) : 0ull;
            u64 r02 = vA ? (((u64)M[lane][4] | ((u64)M[lane][5] << 32)) & V2) : 0ull;
            u64 r11 = B1;
            u64 r12 = vB ? (((u64)M[lane + 64][4] | ((u64)M[lane + 64][5] << 32)) & V2) : 0ull;
            u64 r22 = C2;
            u64 rem0 = V0, rem1 = V1, rem2 = V2;
            P0 = 0; P1 = 0; P2 = 0;
            while (rem0) {
                int i = (int)__builtin_ctzll(rem0);
                u64 w0 = rl64(r00, i), w1 = rl64(r01, i), w2 = rl64(r02, i);
                if (!((w0 >> i) & 1ull)) { stk = i; break; }
                P0 |= 1ull << i;
                rem0 &= ~w0; rem1 &= ~w1; rem2 &= ~w2;
            }
            if (stk == CAP) while (rem1) {
                int i = (int)__builtin_ctzll(rem1);
                u64 w1 = rl64(r11, i), w2 = rl64(r12, i);
                if (!((w1 >> i) & 1ull)) { stk = 64 + i; break; }
                P1 |= 1ull << i;
                rem1 &= ~w1; rem2 &= ~w2;
            }
            if (stk == CAP) while (rem2) {
                int i = (int)__builtin_ctzll(rem2);
                u64 w2 = rl64(r22, i);
                if (!((w2 >> i) & 1ull)) { stk = 128 + i; break; }
                P2 |= 1ull << i;
                rem2 &= ~w2;
            }
        }
        if (lane == 0) { Psh[0] = P0; Psh[1] = P1; Psh[2] = P2; stuck_sh = stk; }
    } else {
        for (int t = tid - 64; t < CAP * 6;     t += 448) ((u32*)sh.f.cl)[t] = 0u;
        for (int t = tid - 64; t < MAXDET * 17; t += 448) out_b[t] = 0.0f;
        for (int t = tid - 64; t < MAXDET;      t += 448) flg_b[t] = 0.0f;
    }
    __syncthreads();

    const u64 P0 = Psh[0], P1 = Psh[1], P2 = Psh[2];
    const int stuck_v = stuck_sh;

    // ---- Phase 5: batched remover-scatter: cl[fc(k)] |= bit(k) ----
    if (tid < C) {
        u64 q0 = ((u64)sh.f.mat32[tid][0] | ((u64)sh.f.mat32[tid][1] << 32)) & P0;
        u64 q1 = ((u64)sh.f.mat32[tid][2] | ((u64)sh.f.mat32[tid][3] << 32)) & P1;
        u64 q2 = ((u64)sh.f.mat32[tid][4] | ((u64)sh.f.mat32[tid][5] << 32)) & P2;
        int fc = -1;
        if      (q0) fc = (int)__builtin_ctzll(q0);
        else if (q1) fc = 64  + (int)__builtin_ctzll(q1);
        else if (q2) fc = 128 + (int)__builtin_ctzll(q2);
        if (fc >= 0) atomicOr(&sh.f.cl[fc][tid >> 5], 1u << (tid & 31));
    }
    __syncthreads();

    // ---- Phase 6: parallel emission by pick rank ----
    bool is_pick = false;
    if (tid < C) {
        is_pick = (tid < 64)  ? ((P0 >> tid) & 1ull)
                : (tid < 128) ? ((P1 >> (tid - 64)) & 1ull)
                              : ((P2 >> (tid - 128)) & 1ull);
    }
    if (is_pick && tid < ((stuck_v < CAP) ? stuck_v : CAP)) {
        int s;
        if (tid < 64)
            s = (int)__popcll(P0 & ((tid ? ((1ull << tid) - 1) : 0ull)));
        else if (tid < 128)
            s = (int)__popcll(P0)
              + (int)__popcll(P1 & (((tid - 64) ? ((1ull << (tid - 64)) - 1) : 0ull)));
        else
            s = (int)__popcll(P0) + (int)__popcll(P1)
              + (int)__popcll(P2 & (((tid - 128) ? ((1ull << (tid - 128)) - 1) : 0ull)));

        u64 c0 = (u64)sh.f.cl[tid][0] | ((u64)sh.f.cl[tid][1] << 32);
        u64 c1 = (u64)sh.f.cl[tid][2] | ((u64)sh.f.cl[tid][3] << 32);
        u64 c2 = (u64)sh.f.cl[tid][4] | ((u64)sh.f.cl[tid][5] << 32);
        int n = (int)__popcll(c0) + (int)__popcll(c1) + (int)__popcll(c2);
        float* orow = out_b + s * 17;
        if (n <= 1) {
            #pragma unroll
            for (int c = 0; c < 17; ++c) orow[c] = sh.f.det[tid][c];
        } else {
            float tot = 0.0f, wc[16];
            #pragma unroll
            for (int c = 0; c < 16; ++c) wc[c] = 0.0f;
            u64 m = c0;
            while (m) { int k = (int)__builtin_ctzll(m); m &= m - 1;
                float sc = sh.f.det[k][16]; tot += sc;
                #pragma unroll
                for (int c = 0; c < 16; ++c) wc[c] += sh.f.det[k][c] * sc; }
            m = c1;
            while (m) { int k = 64 + (int)__builtin_ctzll(m); m &= m - 1;
                float sc = sh.f.det[k][16]; tot += sc;
                #pragma unroll
                for (int c = 0; c < 16; ++c) wc[c] += sh.f.det[k][c] * sc; }
            m = c2;
            while (m) { int k = 128 + (int)__builtin_ctzll(m); m &= m - 1;
                float sc = sh.f.det[k][16]; tot += sc;
                #pragma unroll
                for (int c = 0; c < 16; ++c) wc[c] += sh.f.det[k][c] * sc; }
            float safe = (tot > 0.0f) ? tot : 1.0f;
            #pragma unroll
            for (int c = 0; c < 16; ++c) orow[c] = wc[c] / safe;
            orow[16] = tot / (float)n;
        }
        flg_b[s] = 1.0f;
    }
    // frozen-tail replication for the (unreachable) degenerate case
    if (stuck_v < CAP) {
        int Pb = 0;   // picks before the stuck index
        {
            u64 t0 = P0, t1 = P1, t2 = P2;
            if (stuck_v < 64)       { t0 &= (stuck_v ? ((1ull << stuck_v) - 1) : 0ull); t1 = 0; t2 = 0; }
            else if (stuck_v < 128) { t1 &= (((stuck_v - 64) ? ((1ull << (stuck_v - 64)) - 1) : 0ull)); t2 = 0; }
            else                    { t2 &= (((stuck_v - 128) ? ((1ull << (stuck_v - 128)) - 1) : 0ull)); }
            Pb = (int)__popcll(t0) + (int)__popcll(t1) + (int)__popcll(t2);
        }
        for (int s2 = Pb + tid; s2 < MAXDET; s2 += 512) {
            float* orow = out_b + s2 * 17;
            #pragma unroll
            for (int c = 0; c < 17; ++c) orow[c] = sh.f.det[stuck_v][c];
            flg_b[s2] = 1.0f;
        }
    }
}

extern "C" void kernel_launch(void* const* d_in, const int* in_sizes, int n_in,
                              void* d_out, int out_size, void* d_ws, size_t ws_size,
                              hipStream_t stream) {
    const float* raw_box   = (const float*)d_in[0];
    const float* raw_score = (const float*)d_in[1];
    const float* anchors   = (const float*)d_in[2];
    float* out   = (float*)d_out;
    float* flags = out + (size_t)NBATCH * MAXDET * 17;
    int has_ws = (ws_size >= (size_t)NBATCH * NA * 17 * sizeof(float)) ? 1 : 0;
    nms_kernel<<<NBATCH, 512, 0, stream>>>(raw_box, raw_score, anchors, out, flags,
                                           (float*)d_ws, has_ws);
}